// Round 10
// baseline (262.057 us; speedup 1.0000x reference)
//
#include <hip/hip_runtime.h>

#define NN 100000
#define NE 1600000
#define NB 391          // (NN + 255) >> 8 buckets of 256 dst nodes
#define CAP 5120        // bucket capacity (mean 4092, ~16 sigma headroom)
#define EPB 8192        // edges per block in bucket pass
#define NG1 6250        // gather1 blocks = NN/16
#define NBN 64          // bn-reduce blocks
#define BN_EPS 1e-5f

typedef _Float16 f16;
typedef _Float16 f16x4 __attribute__((ext_vector_type(4)));
typedef _Float16 f16x8 __attribute__((ext_vector_type(8)));
typedef float f32x4v __attribute__((ext_vector_type(4)));

// ---------------- kInit: cursors + stats/done zero + fp16 transposed weights ----------------
__global__ __launch_bounds__(256) void kInit(const float* __restrict__ W1,
                                             const float* __restrict__ W2,
                                             f16* __restrict__ W1t,
                                             f16* __restrict__ W2t,
                                             int* __restrict__ curD,
                                             int* __restrict__ curS,
                                             float* __restrict__ stats,
                                             int* __restrict__ done) {
    int idx = blockIdx.x * 256 + threadIdx.x;
    if (idx < NB) { curD[idx] = idx * CAP; curS[idx] = idx * CAP; }
    if (idx < 512) stats[idx] = 0.f;
    if (idx == 512) done[0] = 0;
    if (idx < 16384) {
        int n = idx >> 7, k = idx & 127;
        W1t[idx] = (f16)W1[k * 128 + n];
    } else if (idx < 24576) {
        int j = idx - 16384;
        int n = j >> 7, k = j & 127;
        W2t[j] = (f16)W2[k * 64 + n];
    }
}

// ---------------- kC: bucket edges by dst>>8 (pairs) and src>>8 (srcBuck), single global read ----------------
__global__ __launch_bounds__(512) void kC(const int* __restrict__ src,
                                          const int* __restrict__ dst,
                                          int* __restrict__ curD,
                                          int* __restrict__ curS,
                                          unsigned* __restrict__ pairs,
                                          unsigned char* __restrict__ srcBuck) {
    __shared__ int sA[EPB], dA[EPB];
    __shared__ int hD[NB], hS[NB], bD_[NB], bS_[NB];
    int t = threadIdx.x;
    for (int i = t; i < NB; i += 512) { hD[i] = 0; hS[i] = 0; }
    __syncthreads();
    int e0 = blockIdx.x * EPB;
    int ne = min(EPB, NE - e0);
    // single global read: cache edges in LDS, count buckets
    for (int i = t; i < ne; i += 512) {
        int s = src[e0 + i], d = dst[e0 + i];
        sA[i] = s; dA[i] = d;
        atomicAdd(&hD[d >> 8], 1);
        atomicAdd(&hS[s >> 8], 1);
    }
    __syncthreads();
    // reserve global ranges, reset local cursors
    for (int i = t; i < NB; i += 512) {
        bD_[i] = hD[i] ? atomicAdd(&curD[i], hD[i]) : 0;
        bS_[i] = hS[i] ? atomicAdd(&curS[i], hS[i]) : 0;
        hD[i] = 0; hS[i] = 0;
    }
    __syncthreads();
    // place from LDS (packed records; defensive clamp vs capacity overflow)
    for (int i = t; i < ne; i += 512) {
        int s = sA[i], d = dA[i];
        int db = d >> 8, sb = s >> 8;
        int rD = atomicAdd(&hD[db], 1);
        int posD = bD_[db] + rD;
        int limD = (db + 1) * CAP - 1;
        if (posD > limD) posD = limD;
        pairs[posD] = ((unsigned)s << 8) | (unsigned)(d & 255);
        int rS = atomicAdd(&hS[sb], 1);
        int posS = bS_[sb] + rS;
        int limS = (sb + 1) * CAP - 1;
        if (posS > limS) posS = limS;
        srcBuck[posS] = (unsigned char)(s & 255);
    }
}

// ---------------- kDE: blocks [0,NB): per-bucket CSR; [NB,2NB): degO ----------------
__global__ __launch_bounds__(256) void kDE(const unsigned* __restrict__ pairs,
                                           const unsigned char* __restrict__ srcBuck,
                                           const int* __restrict__ curD,
                                           const int* __restrict__ curS,
                                           int* __restrict__ rowS,
                                           int* __restrict__ rowE,
                                           int* __restrict__ col,
                                           int* __restrict__ degO) {
    __shared__ unsigned bufA[CAP];                // 20 KB
    __shared__ int cnt[256], csc[256];
    int t = threadIdx.x;
    if (blockIdx.x < NB) {
        int b = blockIdx.x;
        int p0 = b * CAP;
        int n = min(curD[b] - p0, CAP);
        cnt[t] = 0;
        __syncthreads();
        for (int i = t; i < n; i += 256) {
            unsigned v = __builtin_nontemporal_load(&pairs[p0 + i]);
            bufA[i] = v;
            atomicAdd(&cnt[v & 255u], 1);
        }
        __syncthreads();
        int vN = cnt[t];
        csc[t] = vN;
        __syncthreads();
        for (int off = 1; off < 256; off <<= 1) {
            int x = (t >= off) ? csc[t - off] : 0;
            __syncthreads();
            csc[t] += x;
            __syncthreads();
        }
        int nodeStart = csc[t] - vN;
        int node = b * 256 + t;
        if (node < NN) { rowS[node] = p0 + nodeStart; rowE[node] = p0 + nodeStart + vN; }
        cnt[t] = nodeStart;       // node scatter cursor
        __syncthreads();
        for (int i = t; i < n; i += 256) {
            unsigned v = bufA[i];
            int r = atomicAdd(&cnt[v & 255u], 1);
            col[p0 + r] = (int)(v >> 8);
        }
    } else {
        int b = blockIdx.x - NB;
        cnt[t] = 0;
        __syncthreads();
        int p0 = b * CAP;
        int p1 = min(curS[b], p0 + CAP);
        for (int p = p0 + t; p < p1; p += 256)
            atomicAdd(&cnt[__builtin_nontemporal_load(&srcBuck[p])], 1);
        __syncthreads();
        int node = b * 256 + t;
        if (node < NN) degO[node] = cnt[t];
    }
}

// ---------------- GEMM1 (MFMA f16): x1h = (h .* rsqrt(degO)) @ W1 ----------------
__global__ __launch_bounds__(256) void k_gemm1(const float* __restrict__ h,
                                               const f16* __restrict__ W1t,
                                               const int* __restrict__ degO,
                                               f16* __restrict__ x1h) {
    __shared__ f16 Ah[128 * 128];
    __shared__ f16 Bt[128 * 128];
    __shared__ float rsA[128];
    int tid = threadIdx.x;
    int row0 = blockIdx.x * 128;
    if (tid < 128) {
        int r = row0 + tid;
        float d = (r < NN) ? (float)degO[r] : 1.f;
        rsA[tid] = rsqrtf(fmaxf(d, 1.f));
    }
#pragma unroll
    for (int p = 0; p < 8; ++p) {
        int fi = p * 256 + tid;
        int r = fi >> 4, c = fi & 15;
        uint4 v = *(const uint4*)&W1t[fi * 8];
        *(uint4*)&Bt[r * 128 + ((c ^ (r & 7)) * 8)] = v;
    }
    __syncthreads();
#pragma unroll
    for (int p = 0; p < 16; ++p) {
        int fi = p * 256 + tid;
        int r = fi >> 5, c4 = fi & 31;
        int grow = row0 + r;
        float4 av = float4{0.f, 0.f, 0.f, 0.f};
        if (grow < NN) av = *(const float4*)&h[(size_t)grow * 128 + c4 * 4];
        float rs = rsA[r];
        f16x4 t;
        t[0] = (f16)(av.x * rs); t[1] = (f16)(av.y * rs);
        t[2] = (f16)(av.z * rs); t[3] = (f16)(av.w * rs);
        int c8 = c4 >> 1, off = (c4 & 1) * 4;
        *(f16x4*)&Ah[r * 128 + ((c8 ^ (r & 7)) * 8) + off] = t;
    }
    __syncthreads();
    int l = tid & 63, w = tid >> 6;
    int lr = l & 15, g = l >> 4;
    int m0 = w * 32;
    f16x8 a[2][4];
#pragma unroll
    for (int m = 0; m < 2; ++m)
#pragma unroll
        for (int kk = 0; kk < 4; ++kk) {
            int row = m0 + m * 16 + lr;
            a[m][kk] = *(f16x8*)&Ah[row * 128 + (((kk * 4 + g) ^ (row & 7)) * 8)];
        }
    f32x4v acc[2][8];
#pragma unroll
    for (int m = 0; m < 2; ++m)
#pragma unroll
        for (int n = 0; n < 8; ++n) acc[m][n] = f32x4v{0.f, 0.f, 0.f, 0.f};
#pragma unroll
    for (int n = 0; n < 8; ++n) {
        int colr = n * 16 + lr;
        f16x8 b[4];
#pragma unroll
        for (int kk = 0; kk < 4; ++kk)
            b[kk] = *(f16x8*)&Bt[colr * 128 + (((kk * 4 + g) ^ (colr & 7)) * 8)];
#pragma unroll
        for (int m = 0; m < 2; ++m)
#pragma unroll
            for (int kk = 0; kk < 4; ++kk)
                acc[m][n] = __builtin_amdgcn_mfma_f32_16x16x32_f16(a[m][kk], b[kk], acc[m][n], 0, 0, 0);
    }
    __syncthreads();
#pragma unroll
    for (int m = 0; m < 2; ++m)
#pragma unroll
        for (int n = 0; n < 8; ++n)
#pragma unroll
            for (int q = 0; q < 4; ++q) {
                int row = m0 + m * 16 + g * 4 + q;
                Ah[row * 128 + n * 16 + lr] = (f16)acc[m][n][q];
            }
    __syncthreads();
#pragma unroll
    for (int p = 0; p < 8; ++p) {
        int idx = p * 64 + l;
        int r = idx >> 4, c = idx & 15;
        int row = m0 + r, grow = row0 + row;
        uint4 v = *(uint4*)&Ah[row * 128 + c * 8];
        if (grow < NN) *(uint4*)&x1h[(size_t)grow * 128 + c * 8] = v;
    }
}

// ---------------- gather1: y1h = fp16( (sum_j x1h[col[j]]) * rsqrt(degI) + b1 ) + BN partials ----------------
__global__ __launch_bounds__(256) void k_gather1(const f16* __restrict__ x1h,
                                                 const int* __restrict__ rowS,
                                                 const int* __restrict__ rowE,
                                                 const int* __restrict__ col,
                                                 const float* __restrict__ b1,
                                                 f16* __restrict__ y1h,
                                                 float* __restrict__ part) {
    __shared__ float red[4 * 16 * 16];
    int tid = threadIdx.x;
    int bid = blockIdx.x;
    int node = bid * 16 + (tid >> 4);     // NN = 6250*16 exactly, no tail
    int f8 = tid & 15;
    int s0 = rowS[node], s1 = rowE[node];
    const uint4* x4 = (const uint4*)x1h;
    float acc[8] = {0.f, 0.f, 0.f, 0.f, 0.f, 0.f, 0.f, 0.f};
    int j = s0;
    for (; j + 3 < s1; j += 4) {
        int a0 = __builtin_nontemporal_load(&col[j]);
        int a1 = __builtin_nontemporal_load(&col[j + 1]);
        int a2 = __builtin_nontemporal_load(&col[j + 2]);
        int a3 = __builtin_nontemporal_load(&col[j + 3]);
        uint4 v0 = x4[(size_t)a0 * 16 + f8];
        uint4 v1 = x4[(size_t)a1 * 16 + f8];
        uint4 v2 = x4[(size_t)a2 * 16 + f8];
        uint4 v3 = x4[(size_t)a3 * 16 + f8];
        const f16* h0 = (const f16*)&v0; const f16* h1 = (const f16*)&v1;
        const f16* h2 = (const f16*)&v2; const f16* h3 = (const f16*)&v3;
#pragma unroll
        for (int k = 0; k < 8; ++k)
            acc[k] += (float)h0[k] + (float)h1[k] + (float)h2[k] + (float)h3[k];
    }
    for (; j < s1; ++j) {
        int a = __builtin_nontemporal_load(&col[j]);
        uint4 v = x4[(size_t)a * 16 + f8];
        const f16* hp = (const f16*)&v;
#pragma unroll
        for (int k = 0; k < 8; ++k) acc[k] += (float)hp[k];
    }
    float rs = rsqrtf(fmaxf((float)(s1 - s0), 1.f));
    const float4* b4 = (const float4*)b1;
    float4 ba = b4[f8 * 2], bb = b4[f8 * 2 + 1];
    f16x8 o;
    o[0] = (f16)(acc[0] * rs + ba.x); o[1] = (f16)(acc[1] * rs + ba.y);
    o[2] = (f16)(acc[2] * rs + ba.z); o[3] = (f16)(acc[3] * rs + ba.w);
    o[4] = (f16)(acc[4] * rs + bb.x); o[5] = (f16)(acc[5] * rs + bb.y);
    o[6] = (f16)(acc[6] * rs + bb.z); o[7] = (f16)(acc[7] * rs + bb.w);
    *(f16x8*)&y1h[(size_t)node * 128 + f8 * 8] = o;
    // BN partial sums (on fp16-rounded values, matching what gemm2 will read)
    float sv[8], qv[8];
#pragma unroll
    for (int k = 0; k < 8; ++k) { sv[k] = (float)o[k]; qv[k] = sv[k] * sv[k]; }
#pragma unroll
    for (int mask = 16; mask <= 32; mask <<= 1) {
#pragma unroll
        for (int k = 0; k < 8; ++k) {
            sv[k] += __shfl_xor(sv[k], mask);
            qv[k] += __shfl_xor(qv[k], mask);
        }
    }
    int w = tid >> 6, lane = tid & 63;
    if (lane < 16) {
#pragma unroll
        for (int k = 0; k < 8; ++k) {
            red[w * 256 + lane * 16 + k] = sv[k];
            red[w * 256 + lane * 16 + 8 + k] = qv[k];
        }
    }
    __syncthreads();
    int f8_ = tid & 15, idx = tid >> 4;   // idx 0..7 -> sum, 8..15 -> sumsq
    float tot = red[0 * 256 + f8_ * 16 + idx] + red[1 * 256 + f8_ * 16 + idx]
              + red[2 * 256 + f8_ * 16 + idx] + red[3 * 256 + f8_ * 16 + idx];
    int slot = (idx < 8) ? (f8_ * 8 + idx) : (128 + f8_ * 8 + (idx - 8));
    part[(size_t)bid * 256 + slot] = tot;
}

// ---------------- k_bnfin: reduce partials -> stats; last block computes scale/shift ----------------
__global__ __launch_bounds__(256) void k_bnfin(const float* __restrict__ part,
                                               float* __restrict__ stats,
                                               int* __restrict__ done,
                                               const float* __restrict__ gamma,
                                               const float* __restrict__ beta) {
    int t = threadIdx.x;
    float loc = 0.f;
    for (int b = blockIdx.x; b < NG1; b += gridDim.x)
        loc += part[(size_t)b * 256 + t];
    atomicAdd(&stats[t], loc);
    __threadfence();
    __shared__ int amLast;
    if (t == 0) amLast = (atomicAdd(done, 1) == NBN - 1) ? 1 : 0;
    __syncthreads();
    if (amLast && t < 128) {
        float s  = __hip_atomic_load(&stats[t], __ATOMIC_RELAXED, __HIP_MEMORY_SCOPE_AGENT);
        float sq = __hip_atomic_load(&stats[128 + t], __ATOMIC_RELAXED, __HIP_MEMORY_SCOPE_AGENT);
        float mean = s * (1.f / NN);
        float var = sq * (1.f / NN) - mean * mean;
        var = fmaxf(var, 0.f);
        float sc = gamma[t] * rsqrtf(var + BN_EPS);
        stats[256 + t] = sc;
        stats[384 + t] = beta[t] - mean * sc;
    }
}

// ---------------- GEMM2 (MFMA f16): x2h = (relu(BN(y1)) .* rsqrt(degO)) @ W2 ----------------
__global__ __launch_bounds__(256) void k_gemm2(const f16* __restrict__ y1h,
                                               const f16* __restrict__ W2t,
                                               const int* __restrict__ degO,
                                               const float* __restrict__ stats,
                                               f16* __restrict__ x2h) {
    __shared__ f16 Ah[128 * 128];
    __shared__ f16 Bt[64 * 128];
    __shared__ float sc[128], sh[128], rsA[128];
    int tid = threadIdx.x;
    int row0 = blockIdx.x * 128;
    if (tid < 128) {
        sc[tid] = stats[256 + tid];
        sh[tid] = stats[384 + tid];
        int r = row0 + tid;
        float d = (r < NN) ? (float)degO[r] : 1.f;
        rsA[tid] = rsqrtf(fmaxf(d, 1.f));
    }
#pragma unroll
    for (int p = 0; p < 4; ++p) {
        int fi = p * 256 + tid;
        int r = fi >> 4, c = fi & 15;
        uint4 v = *(const uint4*)&W2t[fi * 8];
        *(uint4*)&Bt[r * 128 + ((c ^ (r & 7)) * 8)] = v;
    }
    __syncthreads();
#pragma unroll
    for (int p = 0; p < 8; ++p) {
        int fi = p * 256 + tid;
        int r = fi >> 4, c = fi & 15;
        int grow = row0 + r;
        f16x8 t;
        if (grow < NN) {
            uint4 v = *(const uint4*)&y1h[(size_t)grow * 128 + c * 8];
            const f16* hp = (const f16*)&v;
            float rs = rsA[r];
#pragma unroll
            for (int i = 0; i < 8; ++i) {
                int ch = c * 8 + i;
                float x = (float)hp[i] * sc[ch] + sh[ch];
                t[i] = (f16)(fmaxf(x, 0.f) * rs);
            }
        } else {
#pragma unroll
            for (int i = 0; i < 8; ++i) t[i] = (f16)0.f;
        }
        *(f16x8*)&Ah[r * 128 + ((c ^ (r & 7)) * 8)] = t;
    }
    __syncthreads();
    int l = tid & 63, w = tid >> 6;
    int lr = l & 15, g = l >> 4;
    int m0 = w * 32;
    f16x8 a[2][4];
#pragma unroll
    for (int m = 0; m < 2; ++m)
#pragma unroll
        for (int kk = 0; kk < 4; ++kk) {
            int row = m0 + m * 16 + lr;
            a[m][kk] = *(f16x8*)&Ah[row * 128 + (((kk * 4 + g) ^ (row & 7)) * 8)];
        }
    f32x4v acc[2][4];
#pragma unroll
    for (int m = 0; m < 2; ++m)
#pragma unroll
        for (int n = 0; n < 4; ++n) acc[m][n] = f32x4v{0.f, 0.f, 0.f, 0.f};
#pragma unroll
    for (int n = 0; n < 4; ++n) {
        int colr = n * 16 + lr;
        f16x8 b[4];
#pragma unroll
        for (int kk = 0; kk < 4; ++kk)
            b[kk] = *(f16x8*)&Bt[colr * 128 + (((kk * 4 + g) ^ (colr & 7)) * 8)];
#pragma unroll
        for (int m = 0; m < 2; ++m)
#pragma unroll
            for (int kk = 0; kk < 4; ++kk)
                acc[m][n] = __builtin_amdgcn_mfma_f32_16x16x32_f16(a[m][kk], b[kk], acc[m][n], 0, 0, 0);
    }
    __syncthreads();
#pragma unroll
    for (int m = 0; m < 2; ++m)
#pragma unroll
        for (int n = 0; n < 4; ++n)
#pragma unroll
            for (int q = 0; q < 4; ++q) {
                int row = m0 + m * 16 + g * 4 + q;
                Ah[row * 64 + n * 16 + lr] = (f16)acc[m][n][q];
            }
    __syncthreads();
#pragma unroll
    for (int p = 0; p < 4; ++p) {
        int idx = p * 64 + l;
        int r = idx >> 3, c = idx & 7;
        int row = m0 + r, grow = row0 + row;
        uint4 v = *(uint4*)&Ah[row * 64 + c * 8];
        if (grow < NN) *(uint4*)&x2h[(size_t)grow * 64 + c * 8] = v;
    }
}

// ---------------- gather2: out = (sum_j x2h[col[j]]) * rsqrt(degI) + b2 (fp32) ----------------
__global__ __launch_bounds__(256) void k_gather2(const f16* __restrict__ x2h,
                                                 const int* __restrict__ rowS,
                                                 const int* __restrict__ rowE,
                                                 const int* __restrict__ col,
                                                 const float* __restrict__ b2,
                                                 float* __restrict__ out) {
    int node = blockIdx.x * 32 + (threadIdx.x >> 3);
    int f8 = threadIdx.x & 7;
    if (node >= NN) return;
    int s0 = rowS[node], s1 = rowE[node];
    const uint4* x4 = (const uint4*)x2h;
    float acc[8] = {0.f, 0.f, 0.f, 0.f, 0.f, 0.f, 0.f, 0.f};
    int j = s0;
    for (; j + 3 < s1; j += 4) {
        int a0 = __builtin_nontemporal_load(&col[j]);
        int a1 = __builtin_nontemporal_load(&col[j + 1]);
        int a2 = __builtin_nontemporal_load(&col[j + 2]);
        int a3 = __builtin_nontemporal_load(&col[j + 3]);
        uint4 v0 = x4[(size_t)a0 * 8 + f8];
        uint4 v1 = x4[(size_t)a1 * 8 + f8];
        uint4 v2 = x4[(size_t)a2 * 8 + f8];
        uint4 v3 = x4[(size_t)a3 * 8 + f8];
        const f16* h0 = (const f16*)&v0; const f16* h1 = (const f16*)&v1;
        const f16* h2 = (const f16*)&v2; const f16* h3 = (const f16*)&v3;
#pragma unroll
        for (int k = 0; k < 8; ++k)
            acc[k] += (float)h0[k] + (float)h1[k] + (float)h2[k] + (float)h3[k];
    }
    for (; j < s1; ++j) {
        int a = __builtin_nontemporal_load(&col[j]);
        uint4 v = x4[(size_t)a * 8 + f8];
        const f16* hp = (const f16*)&v;
#pragma unroll
        for (int k = 0; k < 8; ++k) acc[k] += (float)hp[k];
    }
    float rs = rsqrtf(fmaxf((float)(s1 - s0), 1.f));
    const float4* b4 = (const float4*)b2;
    float4 ba = b4[f8 * 2], bb = b4[f8 * 2 + 1];
    float4 o0, o1;
    o0.x = acc[0] * rs + ba.x; o0.y = acc[1] * rs + ba.y;
    o0.z = acc[2] * rs + ba.z; o0.w = acc[3] * rs + ba.w;
    o1.x = acc[4] * rs + bb.x; o1.y = acc[5] * rs + bb.y;
    o1.z = acc[6] * rs + bb.z; o1.w = acc[7] * rs + bb.w;
    *(float4*)&out[(size_t)node * 64 + f8 * 8] = o0;
    *(float4*)&out[(size_t)node * 64 + f8 * 8 + 4] = o1;
}

extern "C" void kernel_launch(void* const* d_in, const int* in_sizes, int n_in,
                              void* d_out, int out_size, void* d_ws, size_t ws_size,
                              hipStream_t stream) {
    const float* h     = (const float*)d_in[0];
    const float* W1    = (const float*)d_in[1];
    const float* b1    = (const float*)d_in[2];
    const float* W2    = (const float*)d_in[3];
    const float* b2    = (const float*)d_in[4];
    const float* gamma = (const float*)d_in[5];
    const float* beta  = (const float*)d_in[6];
    const int*   src   = (const int*)d_in[7];
    const int*   dst   = (const int*)d_in[8];
    float* out = (float*)d_out;

    const size_t BSZ = (size_t)NB * CAP;    // 2,001,920 slots

    // workspace layout (int units from base)
    int* base = (int*)d_ws;
    float* stats = (float*)base;            // 512
    int* done = base + 512;                 // 1
    int* curD = base + 513;                 // NB
    int* curS = curD + NB;                  // NB
    int* rowS = curS + NB;                  // NN
    int* rowE = rowS + NN;                  // NN
    int* degO = rowE + NN;                  // NN
    int* col  = degO + NN;                  // BSZ ints
    unsigned* pairs = (unsigned*)(col + BSZ);               // BSZ u32
    unsigned char* srcBuck = (unsigned char*)(pairs + BSZ); // BSZ bytes
    float* part = (float*)(pairs + BSZ + (BSZ + 3) / 4);    // NG1*256 floats
    size_t o = (size_t)(col + BSZ - base) + BSZ + (BSZ + 3) / 4 + (size_t)NG1 * 256;
    o = (o + 3) & ~(size_t)3;               // 16B align
    f16* W1t = (f16*)(base + o);            // 16384 halves
    f16* W2t = W1t + 16384;                 // 8192 halves
    o += 8192 + 4096;
    f16* x1h = (f16*)(base + o);            // NN*128 halves
    o += (size_t)NN * 64;
    f16* y1h = (f16*)(base + o);            // NN*128 halves
    f16* x2h = x1h;                         // reuse (x1h dead after gather1)

    kInit<<<97, 256, 0, stream>>>(W1, W2, W1t, W2t, curD, curS, stats, done);

    int bgrid = (NE + EPB - 1) / EPB;       // 196
    kC<<<bgrid, 512, 0, stream>>>(src, dst, curD, curS, pairs, srcBuck);
    kDE<<<2 * NB, 256, 0, stream>>>(pairs, srcBuck, curD, curS, rowS, rowE, col, degO);

    int ggrid = (NN + 127) / 128;           // 782
    k_gemm1<<<ggrid, 256, 0, stream>>>(h, W1t, degO, x1h);
    k_gather1<<<NG1, 256, 0, stream>>>(x1h, rowS, rowE, col, b1, y1h, part);
    k_bnfin<<<NBN, 256, 0, stream>>>(part, stats, done, gamma, beta);
    k_gemm2<<<ggrid, 256, 0, stream>>>(y1h, W2t, degO, stats, x2h);
    k_gather2<<<(NN + 31) / 32, 256, 0, stream>>>(x2h, rowS, rowE, col, b2, out);
}

// Round 11
// 254.891 us; speedup vs baseline: 1.0281x; 1.0281x over previous
//
#include <hip/hip_runtime.h>

#define NN 100000
#define NE 1600000
#define NB 391          // (NN + 255) >> 8 buckets of 256 dst nodes
#define CAP 5120        // bucket capacity (mean 4092, ~16 sigma headroom)
#define EPB 8192        // edges per block in bucket pass
#define NG1 6250        // gather1 blocks = NN/16
#define NBN 64          // bn-reduce blocks
#define BN_EPS 1e-5f

typedef _Float16 f16;
typedef _Float16 f16x4 __attribute__((ext_vector_type(4)));
typedef _Float16 f16x8 __attribute__((ext_vector_type(8)));
typedef float f32x4v __attribute__((ext_vector_type(4)));

// ---------------- kCW: weight transpose (first 48 blocks) + edge bucketing ----------------
// cursors curD/curS are zero-initialized in-bucket OFFSETS (memset), not absolute positions.
__global__ __launch_bounds__(512) void kCW(const int* __restrict__ src,
                                           const int* __restrict__ dst,
                                           const float* __restrict__ W1,
                                           const float* __restrict__ W2,
                                           f16* __restrict__ W1t,
                                           f16* __restrict__ W2t,
                                           int* __restrict__ curD,
                                           int* __restrict__ curS,
                                           unsigned* __restrict__ pairs,
                                           unsigned char* __restrict__ srcBuck) {
    int t = threadIdx.x;
    int gidx = blockIdx.x * 512 + t;
    if (gidx < 16384) {
        int n = gidx >> 7, k = gidx & 127;
        W1t[gidx] = (f16)W1[k * 128 + n];
    } else if (gidx < 24576) {
        int j = gidx - 16384;
        int n = j >> 7, k = j & 127;
        W2t[j] = (f16)W2[k * 64 + n];
    }
    __shared__ int sA[EPB], dA[EPB];
    __shared__ int hD[NB], hS[NB], bD_[NB], bS_[NB];
    for (int i = t; i < NB; i += 512) { hD[i] = 0; hS[i] = 0; }
    __syncthreads();
    int e0 = blockIdx.x * EPB;
    int ne = min(EPB, NE - e0);
    // single global read: cache edges in LDS, count buckets
    for (int i = t; i < ne; i += 512) {
        int s = src[e0 + i], d = dst[e0 + i];
        sA[i] = s; dA[i] = d;
        atomicAdd(&hD[d >> 8], 1);
        atomicAdd(&hS[s >> 8], 1);
    }
    __syncthreads();
    // reserve in-bucket offset ranges, reset local cursors
    for (int i = t; i < NB; i += 512) {
        bD_[i] = hD[i] ? atomicAdd(&curD[i], hD[i]) : 0;
        bS_[i] = hS[i] ? atomicAdd(&curS[i], hS[i]) : 0;
        hD[i] = 0; hS[i] = 0;
    }
    __syncthreads();
    // place from LDS (packed records; defensive clamp vs capacity overflow)
    for (int i = t; i < ne; i += 512) {
        int s = sA[i], d = dA[i];
        int db = d >> 8, sb = s >> 8;
        int rD = atomicAdd(&hD[db], 1);
        int offD = bD_[db] + rD;
        if (offD > CAP - 1) offD = CAP - 1;
        pairs[db * CAP + offD] = ((unsigned)s << 8) | (unsigned)(d & 255);
        int rS = atomicAdd(&hS[sb], 1);
        int offS = bS_[sb] + rS;
        if (offS > CAP - 1) offS = CAP - 1;
        srcBuck[sb * CAP + offS] = (unsigned char)(s & 255);
    }
}

// ---------------- kDE: blocks [0,NB): per-bucket CSR; [NB,2NB): degO ----------------
__global__ __launch_bounds__(256) void kDE(const unsigned* __restrict__ pairs,
                                           const unsigned char* __restrict__ srcBuck,
                                           const int* __restrict__ curD,
                                           const int* __restrict__ curS,
                                           int* __restrict__ rowS,
                                           int* __restrict__ rowE,
                                           int* __restrict__ col,
                                           int* __restrict__ degO) {
    __shared__ unsigned bufA[CAP];                // 20 KB
    __shared__ int cnt[256], csc[256];
    int t = threadIdx.x;
    if (blockIdx.x < NB) {
        int b = blockIdx.x;
        int p0 = b * CAP;
        int n = min(curD[b], CAP);
        cnt[t] = 0;
        __syncthreads();
        for (int i = t; i < n; i += 256) {
            unsigned v = pairs[p0 + i];
            bufA[i] = v;
            atomicAdd(&cnt[v & 255u], 1);
        }
        __syncthreads();
        int vN = cnt[t];
        csc[t] = vN;
        __syncthreads();
        for (int off = 1; off < 256; off <<= 1) {
            int x = (t >= off) ? csc[t - off] : 0;
            __syncthreads();
            csc[t] += x;
            __syncthreads();
        }
        int nodeStart = csc[t] - vN;
        int node = b * 256 + t;
        if (node < NN) { rowS[node] = p0 + nodeStart; rowE[node] = p0 + nodeStart + vN; }
        cnt[t] = nodeStart;       // node scatter cursor
        __syncthreads();
        for (int i = t; i < n; i += 256) {
            unsigned v = bufA[i];
            int r = atomicAdd(&cnt[v & 255u], 1);
            col[p0 + r] = (int)(v >> 8);
        }
    } else {
        int b = blockIdx.x - NB;
        cnt[t] = 0;
        __syncthreads();
        int p0 = b * CAP;
        int n = min(curS[b], CAP);
        for (int p = t; p < n; p += 256)
            atomicAdd(&cnt[srcBuck[p0 + p]], 1);
        __syncthreads();
        int node = b * 256 + t;
        if (node < NN) degO[node] = cnt[t];
    }
}

// ---------------- GEMM1 (MFMA f16): x1h = (h .* rsqrt(degO)) @ W1 ----------------
__global__ __launch_bounds__(256) void k_gemm1(const float* __restrict__ h,
                                               const f16* __restrict__ W1t,
                                               const int* __restrict__ degO,
                                               f16* __restrict__ x1h) {
    __shared__ f16 Ah[128 * 128];
    __shared__ f16 Bt[128 * 128];
    __shared__ float rsA[128];
    int tid = threadIdx.x;
    int row0 = blockIdx.x * 128;
    if (tid < 128) {
        int r = row0 + tid;
        float d = (r < NN) ? (float)degO[r] : 1.f;
        rsA[tid] = rsqrtf(fmaxf(d, 1.f));
    }
#pragma unroll
    for (int p = 0; p < 8; ++p) {
        int fi = p * 256 + tid;
        int r = fi >> 4, c = fi & 15;
        uint4 v = *(const uint4*)&W1t[fi * 8];
        *(uint4*)&Bt[r * 128 + ((c ^ (r & 7)) * 8)] = v;
    }
    __syncthreads();
#pragma unroll
    for (int p = 0; p < 16; ++p) {
        int fi = p * 256 + tid;
        int r = fi >> 5, c4 = fi & 31;
        int grow = row0 + r;
        float4 av = float4{0.f, 0.f, 0.f, 0.f};
        if (grow < NN) av = *(const float4*)&h[(size_t)grow * 128 + c4 * 4];
        float rs = rsA[r];
        f16x4 t;
        t[0] = (f16)(av.x * rs); t[1] = (f16)(av.y * rs);
        t[2] = (f16)(av.z * rs); t[3] = (f16)(av.w * rs);
        int c8 = c4 >> 1, off = (c4 & 1) * 4;
        *(f16x4*)&Ah[r * 128 + ((c8 ^ (r & 7)) * 8) + off] = t;
    }
    __syncthreads();
    int l = tid & 63, w = tid >> 6;
    int lr = l & 15, g = l >> 4;
    int m0 = w * 32;
    f16x8 a[2][4];
#pragma unroll
    for (int m = 0; m < 2; ++m)
#pragma unroll
        for (int kk = 0; kk < 4; ++kk) {
            int row = m0 + m * 16 + lr;
            a[m][kk] = *(f16x8*)&Ah[row * 128 + (((kk * 4 + g) ^ (row & 7)) * 8)];
        }
    f32x4v acc[2][8];
#pragma unroll
    for (int m = 0; m < 2; ++m)
#pragma unroll
        for (int n = 0; n < 8; ++n) acc[m][n] = f32x4v{0.f, 0.f, 0.f, 0.f};
#pragma unroll
    for (int n = 0; n < 8; ++n) {
        int colr = n * 16 + lr;
        f16x8 b[4];
#pragma unroll
        for (int kk = 0; kk < 4; ++kk)
            b[kk] = *(f16x8*)&Bt[colr * 128 + (((kk * 4 + g) ^ (colr & 7)) * 8)];
#pragma unroll
        for (int m = 0; m < 2; ++m)
#pragma unroll
            for (int kk = 0; kk < 4; ++kk)
                acc[m][n] = __builtin_amdgcn_mfma_f32_16x16x32_f16(a[m][kk], b[kk], acc[m][n], 0, 0, 0);
    }
    __syncthreads();
#pragma unroll
    for (int m = 0; m < 2; ++m)
#pragma unroll
        for (int n = 0; n < 8; ++n)
#pragma unroll
            for (int q = 0; q < 4; ++q) {
                int row = m0 + m * 16 + g * 4 + q;
                Ah[row * 128 + n * 16 + lr] = (f16)acc[m][n][q];
            }
    __syncthreads();
#pragma unroll
    for (int p = 0; p < 8; ++p) {
        int idx = p * 64 + l;
        int r = idx >> 4, c = idx & 15;
        int row = m0 + r, grow = row0 + row;
        uint4 v = *(uint4*)&Ah[row * 128 + c * 8];
        if (grow < NN) *(uint4*)&x1h[(size_t)grow * 128 + c * 8] = v;
    }
}

// ---------------- gather1: y1h = fp16( (sum_j x1h[col[j]]) * rsqrt(degI) + b1 ) + BN partials ----------------
__global__ __launch_bounds__(256) void k_gather1(const f16* __restrict__ x1h,
                                                 const int* __restrict__ rowS,
                                                 const int* __restrict__ rowE,
                                                 const int* __restrict__ col,
                                                 const float* __restrict__ b1,
                                                 f16* __restrict__ y1h,
                                                 float* __restrict__ part) {
    __shared__ float red[4 * 16 * 16];
    int tid = threadIdx.x;
    int bid = blockIdx.x;
    int node = bid * 16 + (tid >> 4);     // NN = 6250*16 exactly, no tail
    int f8 = tid & 15;
    int s0 = rowS[node], s1 = rowE[node];
    const uint4* x4 = (const uint4*)x1h;
    float acc[8] = {0.f, 0.f, 0.f, 0.f, 0.f, 0.f, 0.f, 0.f};
    int j = s0;
    for (; j + 3 < s1; j += 4) {
        int a0 = col[j], a1 = col[j + 1], a2 = col[j + 2], a3 = col[j + 3];
        uint4 v0 = x4[(size_t)a0 * 16 + f8];
        uint4 v1 = x4[(size_t)a1 * 16 + f8];
        uint4 v2 = x4[(size_t)a2 * 16 + f8];
        uint4 v3 = x4[(size_t)a3 * 16 + f8];
        const f16* h0 = (const f16*)&v0; const f16* h1 = (const f16*)&v1;
        const f16* h2 = (const f16*)&v2; const f16* h3 = (const f16*)&v3;
#pragma unroll
        for (int k = 0; k < 8; ++k)
            acc[k] += (float)h0[k] + (float)h1[k] + (float)h2[k] + (float)h3[k];
    }
    for (; j < s1; ++j) {
        int a = col[j];
        uint4 v = x4[(size_t)a * 16 + f8];
        const f16* hp = (const f16*)&v;
#pragma unroll
        for (int k = 0; k < 8; ++k) acc[k] += (float)hp[k];
    }
    float rs = rsqrtf(fmaxf((float)(s1 - s0), 1.f));
    const float4* b4 = (const float4*)b1;
    float4 ba = b4[f8 * 2], bb = b4[f8 * 2 + 1];
    f16x8 o;
    o[0] = (f16)(acc[0] * rs + ba.x); o[1] = (f16)(acc[1] * rs + ba.y);
    o[2] = (f16)(acc[2] * rs + ba.z); o[3] = (f16)(acc[3] * rs + ba.w);
    o[4] = (f16)(acc[4] * rs + bb.x); o[5] = (f16)(acc[5] * rs + bb.y);
    o[6] = (f16)(acc[6] * rs + bb.z); o[7] = (f16)(acc[7] * rs + bb.w);
    *(f16x8*)&y1h[(size_t)node * 128 + f8 * 8] = o;
    // BN partial sums (on fp16-rounded values, matching what gemm2 will read)
    float sv[8], qv[8];
#pragma unroll
    for (int k = 0; k < 8; ++k) { sv[k] = (float)o[k]; qv[k] = sv[k] * sv[k]; }
#pragma unroll
    for (int mask = 16; mask <= 32; mask <<= 1) {
#pragma unroll
        for (int k = 0; k < 8; ++k) {
            sv[k] += __shfl_xor(sv[k], mask);
            qv[k] += __shfl_xor(qv[k], mask);
        }
    }
    int w = tid >> 6, lane = tid & 63;
    if (lane < 16) {
#pragma unroll
        for (int k = 0; k < 8; ++k) {
            red[w * 256 + lane * 16 + k] = sv[k];
            red[w * 256 + lane * 16 + 8 + k] = qv[k];
        }
    }
    __syncthreads();
    int f8_ = tid & 15, idx = tid >> 4;   // idx 0..7 -> sum, 8..15 -> sumsq
    float tot = red[0 * 256 + f8_ * 16 + idx] + red[1 * 256 + f8_ * 16 + idx]
              + red[2 * 256 + f8_ * 16 + idx] + red[3 * 256 + f8_ * 16 + idx];
    int slot = (idx < 8) ? (f8_ * 8 + idx) : (128 + f8_ * 8 + (idx - 8));
    part[(size_t)bid * 256 + slot] = tot;
}

// ---------------- k_bnfin: reduce partials -> stats; last block computes scale/shift ----------------
__global__ __launch_bounds__(256) void k_bnfin(const float* __restrict__ part,
                                               float* __restrict__ stats,
                                               int* __restrict__ done,
                                               const float* __restrict__ gamma,
                                               const float* __restrict__ beta) {
    int t = threadIdx.x;
    float loc = 0.f;
    for (int b = blockIdx.x; b < NG1; b += gridDim.x)
        loc += part[(size_t)b * 256 + t];
    atomicAdd(&stats[t], loc);
    __threadfence();
    __shared__ int amLast;
    if (t == 0) amLast = (atomicAdd(done, 1) == NBN - 1) ? 1 : 0;
    __syncthreads();
    if (amLast && t < 128) {
        float s  = __hip_atomic_load(&stats[t], __ATOMIC_RELAXED, __HIP_MEMORY_SCOPE_AGENT);
        float sq = __hip_atomic_load(&stats[128 + t], __ATOMIC_RELAXED, __HIP_MEMORY_SCOPE_AGENT);
        float mean = s * (1.f / NN);
        float var = sq * (1.f / NN) - mean * mean;
        var = fmaxf(var, 0.f);
        float sc = gamma[t] * rsqrtf(var + BN_EPS);
        stats[256 + t] = sc;
        stats[384 + t] = beta[t] - mean * sc;
    }
}

// ---------------- GEMM2 (MFMA f16): x2h = (relu(BN(y1)) .* rsqrt(degO)) @ W2 ----------------
__global__ __launch_bounds__(256) void k_gemm2(const f16* __restrict__ y1h,
                                               const f16* __restrict__ W2t,
                                               const int* __restrict__ degO,
                                               const float* __restrict__ stats,
                                               f16* __restrict__ x2h) {
    __shared__ f16 Ah[128 * 128];
    __shared__ f16 Bt[64 * 128];
    __shared__ float sc[128], sh[128], rsA[128];
    int tid = threadIdx.x;
    int row0 = blockIdx.x * 128;
    if (tid < 128) {
        sc[tid] = stats[256 + tid];
        sh[tid] = stats[384 + tid];
        int r = row0 + tid;
        float d = (r < NN) ? (float)degO[r] : 1.f;
        rsA[tid] = rsqrtf(fmaxf(d, 1.f));
    }
#pragma unroll
    for (int p = 0; p < 4; ++p) {
        int fi = p * 256 + tid;
        int r = fi >> 4, c = fi & 15;
        uint4 v = *(const uint4*)&W2t[fi * 8];
        *(uint4*)&Bt[r * 128 + ((c ^ (r & 7)) * 8)] = v;
    }
    __syncthreads();
#pragma unroll
    for (int p = 0; p < 8; ++p) {
        int fi = p * 256 + tid;
        int r = fi >> 4, c = fi & 15;
        int grow = row0 + r;
        f16x8 t;
        if (grow < NN) {
            uint4 v = *(const uint4*)&y1h[(size_t)grow * 128 + c * 8];
            const f16* hp = (const f16*)&v;
            float rs = rsA[r];
#pragma unroll
            for (int i = 0; i < 8; ++i) {
                int ch = c * 8 + i;
                float x = (float)hp[i] * sc[ch] + sh[ch];
                t[i] = (f16)(fmaxf(x, 0.f) * rs);
            }
        } else {
#pragma unroll
            for (int i = 0; i < 8; ++i) t[i] = (f16)0.f;
        }
        *(f16x8*)&Ah[r * 128 + ((c ^ (r & 7)) * 8)] = t;
    }
    __syncthreads();
    int l = tid & 63, w = tid >> 6;
    int lr = l & 15, g = l >> 4;
    int m0 = w * 32;
    f16x8 a[2][4];
#pragma unroll
    for (int m = 0; m < 2; ++m)
#pragma unroll
        for (int kk = 0; kk < 4; ++kk) {
            int row = m0 + m * 16 + lr;
            a[m][kk] = *(f16x8*)&Ah[row * 128 + (((kk * 4 + g) ^ (row & 7)) * 8)];
        }
    f32x4v acc[2][4];
#pragma unroll
    for (int m = 0; m < 2; ++m)
#pragma unroll
        for (int n = 0; n < 4; ++n) acc[m][n] = f32x4v{0.f, 0.f, 0.f, 0.f};
#pragma unroll
    for (int n = 0; n < 4; ++n) {
        int colr = n * 16 + lr;
        f16x8 b[4];
#pragma unroll
        for (int kk = 0; kk < 4; ++kk)
            b[kk] = *(f16x8*)&Bt[colr * 128 + (((kk * 4 + g) ^ (colr & 7)) * 8)];
#pragma unroll
        for (int m = 0; m < 2; ++m)
#pragma unroll
            for (int kk = 0; kk < 4; ++kk)
                acc[m][n] = __builtin_amdgcn_mfma_f32_16x16x32_f16(a[m][kk], b[kk], acc[m][n], 0, 0, 0);
    }
    __syncthreads();
#pragma unroll
    for (int m = 0; m < 2; ++m)
#pragma unroll
        for (int n = 0; n < 4; ++n)
#pragma unroll
            for (int q = 0; q < 4; ++q) {
                int row = m0 + m * 16 + g * 4 + q;
                Ah[row * 64 + n * 16 + lr] = (f16)acc[m][n][q];
            }
    __syncthreads();
#pragma unroll
    for (int p = 0; p < 4; ++p) {
        int idx = p * 64 + l;
        int r = idx >> 3, c = idx & 7;
        int row = m0 + r, grow = row0 + row;
        uint4 v = *(uint4*)&Ah[row * 64 + c * 8];
        if (grow < NN) *(uint4*)&x2h[(size_t)grow * 64 + c * 8] = v;
    }
}

// ---------------- gather2: out = (sum_j x2h[col[j]]) * rsqrt(degI) + b2 (fp32) ----------------
__global__ __launch_bounds__(256) void k_gather2(const f16* __restrict__ x2h,
                                                 const int* __restrict__ rowS,
                                                 const int* __restrict__ rowE,
                                                 const int* __restrict__ col,
                                                 const float* __restrict__ b2,
                                                 float* __restrict__ out) {
    int node = blockIdx.x * 32 + (threadIdx.x >> 3);
    int f8 = threadIdx.x & 7;
    if (node >= NN) return;
    int s0 = rowS[node], s1 = rowE[node];
    const uint4* x4 = (const uint4*)x2h;
    float acc[8] = {0.f, 0.f, 0.f, 0.f, 0.f, 0.f, 0.f, 0.f};
    int j = s0;
    for (; j + 3 < s1; j += 4) {
        uint4 v[4];
#pragma unroll
        for (int u = 0; u < 4; ++u)
            v[u] = x4[(size_t)col[j + u] * 8 + f8];
#pragma unroll
        for (int u = 0; u < 4; ++u) {
            const f16* hp = (const f16*)&v[u];
#pragma unroll
            for (int k = 0; k < 8; ++k) acc[k] += (float)hp[k];
        }
    }
    for (; j < s1; ++j) {
        uint4 v = x4[(size_t)col[j] * 8 + f8];
        const f16* hp = (const f16*)&v;
#pragma unroll
        for (int k = 0; k < 8; ++k) acc[k] += (float)hp[k];
    }
    float rs = rsqrtf(fmaxf((float)(s1 - s0), 1.f));
    const float4* b4 = (const float4*)b2;
    float4 ba = b4[f8 * 2], bb = b4[f8 * 2 + 1];
    float4 o0, o1;
    o0.x = acc[0] * rs + ba.x; o0.y = acc[1] * rs + ba.y;
    o0.z = acc[2] * rs + ba.z; o0.w = acc[3] * rs + ba.w;
    o1.x = acc[4] * rs + bb.x; o1.y = acc[5] * rs + bb.y;
    o1.z = acc[6] * rs + bb.z; o1.w = acc[7] * rs + bb.w;
    *(float4*)&out[(size_t)node * 64 + f8 * 8] = o0;
    *(float4*)&out[(size_t)node * 64 + f8 * 8 + 4] = o1;
}

extern "C" void kernel_launch(void* const* d_in, const int* in_sizes, int n_in,
                              void* d_out, int out_size, void* d_ws, size_t ws_size,
                              hipStream_t stream) {
    const float* h     = (const float*)d_in[0];
    const float* W1    = (const float*)d_in[1];
    const float* b1    = (const float*)d_in[2];
    const float* W2    = (const float*)d_in[3];
    const float* b2    = (const float*)d_in[4];
    const float* gamma = (const float*)d_in[5];
    const float* beta  = (const float*)d_in[6];
    const int*   src   = (const int*)d_in[7];
    const int*   dst   = (const int*)d_in[8];
    float* out = (float*)d_out;

    const size_t BSZ = (size_t)NB * CAP;    // 2,001,920 slots

    // workspace layout (int units from base)
    int* base = (int*)d_ws;
    float* stats = (float*)base;            // 512
    int* done = base + 512;                 // 1
    int* curD = base + 513;                 // NB (zero-init offsets)
    int* curS = curD + NB;                  // NB
    int* rowS = curS + NB;                  // NN
    int* rowE = rowS + NN;                  // NN
    int* degO = rowE + NN;                  // NN
    int* col  = degO + NN;                  // BSZ ints
    unsigned* pairs = (unsigned*)(col + BSZ);               // BSZ u32
    unsigned char* srcBuck = (unsigned char*)(pairs + BSZ); // BSZ bytes
    float* part = (float*)(pairs + BSZ + (BSZ + 3) / 4);    // NG1*256 floats
    size_t o = (size_t)(col + BSZ - base) + BSZ + (BSZ + 3) / 4 + (size_t)NG1 * 256;
    o = (o + 3) & ~(size_t)3;               // 16B align
    f16* W1t = (f16*)(base + o);            // 16384 halves
    f16* W2t = W1t + 16384;                 // 8192 halves
    o += 8192 + 4096;
    f16* x1h = (f16*)(base + o);            // NN*128 halves
    o += (size_t)NN * 64;
    f16* y1h = (f16*)(base + o);            // NN*128 halves
    f16* x2h = x1h;                         // reuse (x1h dead after gather1)

    // zero stats + done + cursors (contiguous)
    hipMemsetAsync(base, 0, (size_t)(513 + 2 * NB) * 4, stream);

    int bgrid = (NE + EPB - 1) / EPB;       // 196 (>= 48 needed for weight prep)
    kCW<<<bgrid, 512, 0, stream>>>(src, dst, W1, W2, W1t, W2t, curD, curS, pairs, srcBuck);
    kDE<<<2 * NB, 256, 0, stream>>>(pairs, srcBuck, curD, curS, rowS, rowE, col, degO);

    int ggrid = (NN + 127) / 128;           // 782
    k_gemm1<<<ggrid, 256, 0, stream>>>(h, W1t, degO, x1h);
    k_gather1<<<NG1, 256, 0, stream>>>(x1h, rowS, rowE, col, b1, y1h, part);
    k_bnfin<<<NBN, 256, 0, stream>>>(part, stats, done, gamma, beta);
    k_gemm2<<<ggrid, 256, 0, stream>>>(y1h, W2t, degO, stats, x2h);
    k_gather2<<<(NN + 31) / 32, 256, 0, stream>>>(x2h, rowS, rowE, col, b2, out);
}